// Round 7
// baseline (230.947 us; speedup 1.0000x reference)
//
#include <hip/hip_runtime.h>

#define Bn   2
#define Cn   64
#define Dd   8
#define Hd   128
#define Wd   128
#define HW   16384
#define DHW  131072     // 2^17
#define NPOS 262144     // 2^18
#define NELEM 16777216

typedef __attribute__((ext_vector_type(8))) short short8;
typedef __attribute__((ext_vector_type(4))) float floatx4;
typedef __attribute__((ext_vector_type(4))) unsigned short ushort4v;

__device__ __forceinline__ short f2bf(float f) {
    union { float f; unsigned u; } v; v.f = f;
    unsigned r = (v.u + 0x7FFFu + ((v.u >> 16) & 1u)) >> 16;   // RNE
    return (short)r;
}
__device__ __forceinline__ float bf2f(short s) {
    union { unsigned u; float f; } v; v.u = ((unsigned)(unsigned short)s) << 16;
    return v.f;
}
// Cheap truncation split: hi = upper16(f), lo = trunc16(f - hi). ~4 VALU ops.
// Pair error ~2^-17 relative — fp32-class for K=64 GEMMs.
__device__ __forceinline__ void split2(float f, short& hi, short& lo) {
    union { float f; unsigned u; } a; a.f = f;
    unsigned hu = a.u & 0xFFFF0000u;
    hi = (short)(hu >> 16);
    union { unsigned u; float f; } hb; hb.u = hu;
    union { float f; unsigned u; } lb; lb.f = f - hb.f;
    lo = (short)(lb.u >> 16);
}

// ---------------------------------------------------------------------------
// k_prep: split-bf16 weights. Wh{h,l}[80][64]: rows 0..63 = head_w,
// rows 64..66 = V^T @ head_w (folds Vp), rows 67..79 = 0. Wt{h,l}[64][64].
// ---------------------------------------------------------------------------
__global__ __launch_bounds__(256) void k_prep(const float* __restrict__ head_w,
                                              const float* __restrict__ tail_w,
                                              const float* __restrict__ V_w,
                                              short* __restrict__ Whh, short* __restrict__ Whl,
                                              short* __restrict__ Wth, short* __restrict__ Wtl)
{
    int t = threadIdx.x;
#pragma unroll
    for (int rep = 0; rep < 16; ++rep) {
        int idx = rep * 256 + t;            // 4096
        short hh, hl;
        split2(head_w[idx], hh, hl);
        Whh[idx] = hh; Whl[idx] = hl;
        split2(tail_w[idx], hh, hl);
        Wth[idx] = hh; Wtl[idx] = hl;
    }
    if (t < 192) {                          // VW[r][i] = sum_c V[c][r]*W[c][i]
        int r = t >> 6, i = t & 63;
        float s = 0.f;
        for (int cc = 0; cc < 64; ++cc) s += V_w[cc * 3 + r] * head_w[cc * 64 + i];
        short hh, hl;
        split2(s, hh, hl);
        Whh[(64 + r) * 64 + i] = hh;
        Whl[(64 + r) * 64 + i] = hl;
    }
#pragma unroll
    for (int rep = 0; rep < 4; ++rep) {     // zero rows 67..79 (832 entries)
        int idx = rep * 256 + t;
        if (idx < 832) { Whh[67 * 64 + idx] = 0; Whl[67 * 64 + idx] = 0; }
    }
}

// ---------------------------------------------------------------------------
// k_headm: [h | Vp] = Wh[80x64] @ x via split-bf16 MFMA (fp32-equivalent,
// 3-product: al*bh + ah*bl + ah*bh). DIRECT-FRAGMENT version:
//  - X never touches LDS: block=128 positions, each wave owns a disjoint
//    32-pos M-slice -> zero cross-wave X reuse. Each lane loads its MFMA
//    A-fragment straight from global (ch = ks*32+(lane>>4)*8+j,
//    pos = s0+(w*2+mt)*16+(lane&15); derived from the proven staging map)
//    and splits in-register.
//  - C stored directly: lane holds 4 consecutive positions at one output
//    channel (o = nt*16+(lane&15), pos = w*32+mt*16+quad*4) -> aligned
//    float4 stores, 64B-contiguous per 4-lane o-group. No Cb bounce.
// LDS = B only (20 KB). Numerics identical to the staged version.
// ---------------------------------------------------------------------------
__global__ __launch_bounds__(256) void k_headm(const float* __restrict__ x,
                                               const short* __restrict__ Whh,
                                               const short* __restrict__ Whl,
                                               float* __restrict__ h,
                                               float* __restrict__ Vp)
{
    __shared__ __align__(16) short Bh[80 * 64];   // 10 KB
    __shared__ __align__(16) short Bl[80 * 64];   // 10 KB

    int t    = threadIdx.x;
    int lane = t & 63;
    int w    = t >> 6;
    int p0 = blockIdx.x * 128;
    int b  = p0 >> 17;
    int s0 = p0 & (DHW - 1);
    const float* xb = x + ((size_t)b * Cn) * DHW + s0;

    int ch0 = (lane >> 4) * 8;
    int px  = w * 32 + (lane & 15);

    short8 ah[2][2], al[2][2];                    // [ks][mt]
#pragma unroll
    for (int ks = 0; ks < 2; ++ks)
#pragma unroll
        for (int mt = 0; mt < 2; ++mt)
#pragma unroll
            for (int j = 0; j < 8; ++j) {
                short hh, hl;
                split2(xb[(size_t)(ks * 32 + ch0 + j) * DHW + px + mt * 16], hh, hl);
                ah[ks][mt][j] = hh; al[ks][mt][j] = hl;
            }

#pragma unroll
    for (int pass = 0; pass < 3; ++pass) {   // 640 16B-units of Wh
        int unit = pass * 256 + t;
        if (unit < 640) {
            int o   = unit - (unit / 80) * 80;
            int oc  = unit / 80;
            int in0 = oc * 8;
            int blk  = ((o >> 4) << 1) | (in0 >> 5);
            int slot = (((in0 >> 3) & 3) << 4) | (o & 15);
            *(short8*)&Bh[(blk * 64 + slot) * 8] = *(const short8*)&Whh[o * 64 + in0];
            *(short8*)&Bl[(blk * 64 + slot) * 8] = *(const short8*)&Whl[o * 64 + in0];
        }
    }
    __syncthreads();

    floatx4 acc[2][5];
#pragma unroll
    for (int mt = 0; mt < 2; ++mt)
#pragma unroll
        for (int nt = 0; nt < 5; ++nt) acc[mt][nt] = (floatx4)0.f;

    const short8* BhV = (const short8*)Bh;
    const short8* BlV = (const short8*)Bl;
#pragma unroll
    for (int ks = 0; ks < 2; ++ks)
#pragma unroll
        for (int nt = 0; nt < 5; ++nt) {
            short8 bh = BhV[(nt * 2 + ks) * 64 + lane];
            short8 bl = BlV[(nt * 2 + ks) * 64 + lane];
            acc[0][nt] = __builtin_amdgcn_mfma_f32_16x16x32_bf16(al[ks][0], bh, acc[0][nt], 0, 0, 0);
            acc[0][nt] = __builtin_amdgcn_mfma_f32_16x16x32_bf16(ah[ks][0], bl, acc[0][nt], 0, 0, 0);
            acc[0][nt] = __builtin_amdgcn_mfma_f32_16x16x32_bf16(ah[ks][0], bh, acc[0][nt], 0, 0, 0);
            acc[1][nt] = __builtin_amdgcn_mfma_f32_16x16x32_bf16(al[ks][1], bh, acc[1][nt], 0, 0, 0);
            acc[1][nt] = __builtin_amdgcn_mfma_f32_16x16x32_bf16(ah[ks][1], bl, acc[1][nt], 0, 0, 0);
            acc[1][nt] = __builtin_amdgcn_mfma_f32_16x16x32_bf16(ah[ks][1], bh, acc[1][nt], 0, 0, 0);
        }

    int outc = lane & 15;
    int quad = lane >> 4;
#pragma unroll
    for (int mt = 0; mt < 2; ++mt)
#pragma unroll
        for (int nt = 0; nt < 5; ++nt) {
            int o   = nt * 16 + outc;
            int pos = s0 + w * 32 + mt * 16 + quad * 4;
            if (o < 64) {
                *(floatx4*)&h[((size_t)(b * Cn + o)) * DHW + pos] = acc[mt][nt];
            } else if (o < 67) {
                *(floatx4*)&Vp[((size_t)(b * 3 + (o - 64))) * DHW + pos] = acc[mt][nt];
            }
        }
}

// ---------------------------------------------------------------------------
// k_uv: fp32 depthwise 3x3x3 (replicate pad) -> l2norm over r -> dot Vp.
// Slice-major register schedule; 2-row tile / 16 KB LDS (best wall config).
// h stays fp32 (bf16-h FAILED the gate: pre-norm error is amplified by the
// normalization at degenerate-norm points — absmax 1.125 > 1.11). UV written
// bf16 (post-norm precision — safe, verified).
// ---------------------------------------------------------------------------
__global__ __launch_bounds__(256) void k_uv(const float* __restrict__ h,
                                            const float* __restrict__ Vp,
                                            const float* __restrict__ U_w,
                                            unsigned short* __restrict__ UVq)
{
    __shared__ float tile[Dd][4][Wd];   // 16 KB

    int blk = blockIdx.x;
    int yt  = blk & 63;
    int bc  = blk >> 6;                 // b*64 + c
    int b   = bc >> 6;
    int y0  = yt * 2;
    int t   = threadIdx.x;

    const float* hb = h + (size_t)bc * DHW;
#pragma unroll
    for (int rep = 0; rep < 4; ++rep) {   // 1024 float4 units
        int idx = rep * 256 + t;
        int d   = idx >> 7;
        int rem = idx & 127;
        int yr  = rem >> 5;
        int x4  = (rem & 31) * 4;
        int zy  = y0 - 1 + yr;
        zy = zy < 0 ? 0 : (zy > Hd - 1 ? Hd - 1 : zy);
        *(floatx4*)&tile[d][yr][x4] = *(const floatx4*)(hb + d * HW + zy * Wd + x4);
    }
    __syncthreads();

    int xx = t & 127;
    int yr = t >> 7;
    int y  = y0 + yr;
    int xm = xx - 1; if (xm < 0) xm = 0;
    int xp = xx + 1; if (xp > Wd - 1) xp = Wd - 1;

    float a0[8], a1[8], a2[8];
#pragma unroll
    for (int d = 0; d < 8; ++d) { a0[d] = 0.f; a1[d] = 0.f; a2[d] = 0.f; }

#define CONTRIB(dd, dk)                                                   \
    {                                                                     \
        _Pragma("unroll")                                                 \
        for (int kh = 0; kh < 3; ++kh) {                                  \
            _Pragma("unroll")                                             \
            for (int kw = 0; kw < 3; ++kw) {                              \
                const int kk = (((dk) * 3 + kh) * 3 + kw) * 3;            \
                a0[dd] += v[kh][kw] * U_w[kk + 0];                        \
                a1[dd] += v[kh][kw] * U_w[kk + 1];                        \
                a2[dd] += v[kh][kw] * U_w[kk + 2];                        \
            }                                                             \
        }                                                                 \
    }

#pragma unroll
    for (int sl = 0; sl < 8; ++sl) {
        float v[3][3];
#pragma unroll
        for (int kh = 0; kh < 3; ++kh) {
            const float* row = &tile[sl][yr + kh][0];
            v[kh][0] = row[xm]; v[kh][1] = row[xx]; v[kh][2] = row[xp];
        }
        CONTRIB(sl, 1);                         // dk=1 -> d = sl
        if (sl == 0) CONTRIB(0, 0);             // replicate clamp low
        if (sl < 7)  CONTRIB(sl + 1, 0);        // dk=0 -> d = sl+1
        if (sl > 0)  CONTRIB(sl - 1, 2);        // dk=2 -> d = sl-1
        if (sl == 7) CONTRIB(7, 2);             // replicate clamp high
    }
#undef CONTRIB

    const float* vpb    = Vp + (size_t)b * 3 * DHW + y * Wd + xx;
    unsigned short* uvb = UVq + (size_t)bc * DHW + y * Wd + xx;
#pragma unroll
    for (int d = 0; d < 8; ++d) {
        float nrm = sqrtf(a0[d] * a0[d] + a1[d] * a1[d] + a2[d] * a2[d]);
        float inv = 1.f / (1e-6f + nrm);
        float uv = (a0[d] * vpb[(size_t)d * HW]
                  + a1[d] * vpb[(size_t)DHW + d * HW]
                  + a2[d] * vpb[(size_t)2 * DHW + d * HW]) * inv;
        uvb[(size_t)d * HW] = (unsigned short)f2bf(uv);
    }
}

// ---------------------------------------------------------------------------
// k_tailm: out = Wt[64x64] @ UV(bf16) via MFMA; W split (a*bh + a*bl).
// DIRECT-FRAGMENT version (same derivation as k_headm): A-fragments loaded
// straight from global bf16 (no split2, no X-LDS), C stored directly as
// aligned float4. LDS = B only (16 KB).
// ---------------------------------------------------------------------------
__global__ __launch_bounds__(256) void k_tailm(const unsigned short* __restrict__ UVq,
                                               const short* __restrict__ Wth,
                                               const short* __restrict__ Wtl,
                                               float* __restrict__ out)
{
    __shared__ __align__(16) short Bh[64 * 64];   // 8 KB
    __shared__ __align__(16) short Bl[64 * 64];   // 8 KB

    int t    = threadIdx.x;
    int lane = t & 63;
    int w    = t >> 6;
    int p0 = blockIdx.x * 128;
    int b  = p0 >> 17;
    int s0 = p0 & (DHW - 1);
    const unsigned short* uq = UVq + ((size_t)b * Cn) * DHW + s0;

    int ch0 = (lane >> 4) * 8;
    int px  = w * 32 + (lane & 15);

    short8 a[2][2];                               // [ks][mt]
#pragma unroll
    for (int ks = 0; ks < 2; ++ks)
#pragma unroll
        for (int mt = 0; mt < 2; ++mt)
#pragma unroll
            for (int j = 0; j < 8; ++j)
                a[ks][mt][j] = (short)uq[(size_t)(ks * 32 + ch0 + j) * DHW + px + mt * 16];

#pragma unroll
    for (int pass = 0; pass < 2; ++pass) {   // 512 16B-units of Wt
        int unit = pass * 256 + t;
        int o    = unit & 63;
        int oc   = unit >> 6;
        int in0  = oc * 8;
        int blk  = ((o >> 4) << 1) | (in0 >> 5);
        int slot = (((in0 >> 3) & 3) << 4) | (o & 15);
        *(short8*)&Bh[(blk * 64 + slot) * 8] = *(const short8*)&Wth[o * 64 + in0];
        *(short8*)&Bl[(blk * 64 + slot) * 8] = *(const short8*)&Wtl[o * 64 + in0];
    }
    __syncthreads();

    floatx4 acc[2][4];
#pragma unroll
    for (int mt = 0; mt < 2; ++mt)
#pragma unroll
        for (int nt = 0; nt < 4; ++nt) acc[mt][nt] = (floatx4)0.f;

    const short8* BhV = (const short8*)Bh;
    const short8* BlV = (const short8*)Bl;
#pragma unroll
    for (int ks = 0; ks < 2; ++ks)
#pragma unroll
        for (int nt = 0; nt < 4; ++nt) {
            short8 bh = BhV[(nt * 2 + ks) * 64 + lane];
            short8 bl = BlV[(nt * 2 + ks) * 64 + lane];
            acc[0][nt] = __builtin_amdgcn_mfma_f32_16x16x32_bf16(a[ks][0], bl, acc[0][nt], 0, 0, 0);
            acc[0][nt] = __builtin_amdgcn_mfma_f32_16x16x32_bf16(a[ks][0], bh, acc[0][nt], 0, 0, 0);
            acc[1][nt] = __builtin_amdgcn_mfma_f32_16x16x32_bf16(a[ks][1], bl, acc[1][nt], 0, 0, 0);
            acc[1][nt] = __builtin_amdgcn_mfma_f32_16x16x32_bf16(a[ks][1], bh, acc[1][nt], 0, 0, 0);
        }

    int outc = lane & 15;
    int quad = lane >> 4;
#pragma unroll
    for (int mt = 0; mt < 2; ++mt)
#pragma unroll
        for (int nt = 0; nt < 4; ++nt) {
            int o   = nt * 16 + outc;
            int pos = s0 + w * 32 + mt * 16 + quad * 4;
            *(floatx4*)&out[((size_t)(b * Cn + o)) * DHW + pos] = acc[mt][nt];
        }
}

extern "C" void kernel_launch(void* const* d_in, const int* in_sizes, int n_in,
                              void* d_out, int out_size, void* d_ws, size_t ws_size,
                              hipStream_t stream)
{
    const float* x      = (const float*)d_in[0];
    const float* head_w = (const float*)d_in[1];
    const float* tail_w = (const float*)d_in[2];
    const float* U_w    = (const float*)d_in[3];
    const float* V_w    = (const float*)d_in[4];
    float* out = (float*)d_out;

    // ws: h fp32 (64MB) | Vp fp32 (3MB) | UVq bf16 (32MB) | split weights
    float* h   = (float*)d_ws;
    float* Vp  = h + (size_t)NELEM;
    unsigned short* UVq = (unsigned short*)(Vp + (size_t)Bn * 3 * DHW);
    short* Whh = (short*)(UVq + (size_t)NELEM);
    short* Whl = Whh + 80 * 64;
    short* Wth = Whl + 80 * 64;
    short* Wtl = Wth + 64 * 64;

    k_prep<<<1, 256, 0, stream>>>(head_w, tail_w, V_w, Whh, Whl, Wth, Wtl);
    k_headm<<<NPOS / 128, 256, 0, stream>>>(x, Whh, Whl, h, Vp);
    k_uv<<<Bn * Cn * (Hd / 2), 256, 0, stream>>>(h, Vp, U_w, UVq);
    k_tailm<<<NPOS / 128, 256, 0, stream>>>(UVq, Wth, Wtl, out);
}

// Round 8
// 224.466 us; speedup vs baseline: 1.0289x; 1.0289x over previous
//
#include <hip/hip_runtime.h>

#define Bn   2
#define Cn   64
#define Dd   8
#define Hd   128
#define Wd   128
#define HW   16384
#define DHW  131072     // 2^17
#define NPOS 262144     // 2^18
#define NELEM 16777216

typedef __attribute__((ext_vector_type(8))) short short8;
typedef __attribute__((ext_vector_type(4))) float floatx4;
typedef __attribute__((ext_vector_type(2))) float floatx2;
typedef __attribute__((ext_vector_type(4))) unsigned short ushort4v;

__device__ __forceinline__ short f2bf(float f) {
    union { float f; unsigned u; } v; v.f = f;
    unsigned r = (v.u + 0x7FFFu + ((v.u >> 16) & 1u)) >> 16;   // RNE
    return (short)r;
}
__device__ __forceinline__ float bf2f(short s) {
    union { unsigned u; float f; } v; v.u = ((unsigned)(unsigned short)s) << 16;
    return v.f;
}
// Cheap truncation split: hi = upper16(f), lo = trunc16(f - hi). ~4 VALU ops.
// Pair error ~2^-17 relative — fp32-class for K=64 GEMMs.
__device__ __forceinline__ void split2(float f, short& hi, short& lo) {
    union { float f; unsigned u; } a; a.f = f;
    unsigned hu = a.u & 0xFFFF0000u;
    hi = (short)(hu >> 16);
    union { unsigned u; float f; } hb; hb.u = hu;
    union { float f; unsigned u; } lb; lb.f = f - hb.f;
    lo = (short)(lb.u >> 16);
}

// ---------------------------------------------------------------------------
// k_prep: split-bf16 weights. Wh{h,l}[80][64]: rows 0..63 = head_w,
// rows 64..66 = V^T @ head_w (folds Vp), rows 67..79 = 0. Wt{h,l}[64][64].
// ---------------------------------------------------------------------------
__global__ __launch_bounds__(256) void k_prep(const float* __restrict__ head_w,
                                              const float* __restrict__ tail_w,
                                              const float* __restrict__ V_w,
                                              short* __restrict__ Whh, short* __restrict__ Whl,
                                              short* __restrict__ Wth, short* __restrict__ Wtl)
{
    int t = threadIdx.x;
#pragma unroll
    for (int rep = 0; rep < 16; ++rep) {
        int idx = rep * 256 + t;            // 4096
        short hh, hl;
        split2(head_w[idx], hh, hl);
        Whh[idx] = hh; Whl[idx] = hl;
        split2(tail_w[idx], hh, hl);
        Wth[idx] = hh; Wtl[idx] = hl;
    }
    if (t < 192) {                          // VW[r][i] = sum_c V[c][r]*W[c][i]
        int r = t >> 6, i = t & 63;
        float s = 0.f;
        for (int cc = 0; cc < 64; ++cc) s += V_w[cc * 3 + r] * head_w[cc * 64 + i];
        short hh, hl;
        split2(s, hh, hl);
        Whh[(64 + r) * 64 + i] = hh;
        Whl[(64 + r) * 64 + i] = hl;
    }
#pragma unroll
    for (int rep = 0; rep < 4; ++rep) {     // zero rows 67..79 (832 entries)
        int idx = rep * 256 + t;
        if (idx < 832) { Whh[67 * 64 + idx] = 0; Whl[67 * 64 + idx] = 0; }
    }
}

// ---------------------------------------------------------------------------
// k_headm: [h | Vp] = Wh[80x64] @ x via split-bf16 MFMA (fp32-equivalent).
// 3-product split: ah*bh + ah*bl + al*bh (al*bl ~2^-16 rel, dropped).
// R5-verified staged version: X through LDS (256B-contiguous loads), Cb
// epilogue transpose (512B-contiguous stores). R7's direct-fragment variant
// regressed (+11us): the LDS bounces buy access-granularity, keep them.
// ---------------------------------------------------------------------------
__global__ __launch_bounds__(256) void k_headm(const float* __restrict__ x,
                                               const short* __restrict__ Whh,
                                               const short* __restrict__ Whl,
                                               float* __restrict__ h,
                                               float* __restrict__ Vp)
{
    __shared__ __align__(16) char smem[52 * 1024];
    short* Xh = (short*)smem;                    // 16 KB
    short* Xl = (short*)(smem + 16 * 1024);      // 16 KB
    short* Bh = (short*)(smem + 32 * 1024);      // 10 KB
    short* Bl = (short*)(smem + 42 * 1024);      // 10 KB
    float* Cb = (float*)smem;                    // epilogue: 80*132*4 = 42240 B

    int t  = threadIdx.x;
    int p0 = blockIdx.x * 128;
    int b  = p0 >> 17;
    int s0 = p0 & (DHW - 1);
    const float* xb = x + ((size_t)b * Cn) * DHW + s0;

    int pp = t & 127;
    int ho = t >> 7;
#pragma unroll
    for (int pass = 0; pass < 4; ++pass) {
        int in0 = pass * 16 + ho * 8;
        short8 vh, vl;
#pragma unroll
        for (int j = 0; j < 8; ++j) {
            short hh, hl;
            split2(xb[(size_t)(in0 + j) * DHW + pp], hh, hl);
            vh[j] = hh; vl[j] = hl;
        }
        int blk  = ((in0 >> 5) << 3) | (pp >> 4);
        int slot = (((in0 >> 3) & 3) << 4) | (pp & 15);
        *(short8*)&Xh[(blk * 64 + slot) * 8] = vh;
        *(short8*)&Xl[(blk * 64 + slot) * 8] = vl;
    }
#pragma unroll
    for (int pass = 0; pass < 3; ++pass) {   // 640 16B-units of Wh
        int unit = pass * 256 + t;
        if (unit < 640) {
            int o   = unit - (unit / 80) * 80;
            int oc  = unit / 80;
            int in0 = oc * 8;
            int blk  = ((o >> 4) << 1) | (in0 >> 5);
            int slot = (((in0 >> 3) & 3) << 4) | (o & 15);
            *(short8*)&Bh[(blk * 64 + slot) * 8] = *(const short8*)&Whh[o * 64 + in0];
            *(short8*)&Bl[(blk * 64 + slot) * 8] = *(const short8*)&Whl[o * 64 + in0];
        }
    }
    __syncthreads();

    int lane = t & 63;
    int w    = t >> 6;
    floatx4 acc[2][5];
#pragma unroll
    for (int mt = 0; mt < 2; ++mt)
#pragma unroll
        for (int nt = 0; nt < 5; ++nt) acc[mt][nt] = (floatx4)0.f;

    const short8* XhV = (const short8*)Xh;
    const short8* XlV = (const short8*)Xl;
    const short8* BhV = (const short8*)Bh;
    const short8* BlV = (const short8*)Bl;
#pragma unroll
    for (int ks = 0; ks < 2; ++ks) {
        short8 ah0 = XhV[(ks * 8 + w * 2 + 0) * 64 + lane];
        short8 ah1 = XhV[(ks * 8 + w * 2 + 1) * 64 + lane];
        short8 al0 = XlV[(ks * 8 + w * 2 + 0) * 64 + lane];
        short8 al1 = XlV[(ks * 8 + w * 2 + 1) * 64 + lane];
#pragma unroll
        for (int nt = 0; nt < 5; ++nt) {
            short8 bh = BhV[(nt * 2 + ks) * 64 + lane];
            short8 bl = BlV[(nt * 2 + ks) * 64 + lane];
            acc[0][nt] = __builtin_amdgcn_mfma_f32_16x16x32_bf16(al0, bh, acc[0][nt], 0, 0, 0);
            acc[0][nt] = __builtin_amdgcn_mfma_f32_16x16x32_bf16(ah0, bl, acc[0][nt], 0, 0, 0);
            acc[0][nt] = __builtin_amdgcn_mfma_f32_16x16x32_bf16(ah0, bh, acc[0][nt], 0, 0, 0);
            acc[1][nt] = __builtin_amdgcn_mfma_f32_16x16x32_bf16(al1, bh, acc[1][nt], 0, 0, 0);
            acc[1][nt] = __builtin_amdgcn_mfma_f32_16x16x32_bf16(ah1, bl, acc[1][nt], 0, 0, 0);
            acc[1][nt] = __builtin_amdgcn_mfma_f32_16x16x32_bf16(ah1, bh, acc[1][nt], 0, 0, 0);
        }
    }

    __syncthreads();                        // frag reads done; reuse LDS as Cb
    int outc = lane & 15;
    int quad = lane >> 4;
#pragma unroll
    for (int mt = 0; mt < 2; ++mt)
#pragma unroll
        for (int nt = 0; nt < 5; ++nt) {
            int o   = nt * 16 + outc;
            int pos = w * 32 + mt * 16 + quad * 4;
            *(floatx4*)&Cb[o * 132 + pos] = acc[mt][nt];
        }
    __syncthreads();

    int xr = (t & 31) * 4;                  // 0..124
    int ob = t >> 5;                        // 0..7
#pragma unroll
    for (int pass = 0; pass < 9; ++pass) {
        int o = pass * 8 + ob;
        floatx4 vv = *(const floatx4*)&Cb[o * 132 + xr];
        if (o < 64) {
            *(floatx4*)&h[((size_t)(b * Cn + o)) * DHW + s0 + xr] = vv;
        } else if (o < 67) {
            *(floatx4*)&Vp[((size_t)(b * 3 + (o - 64))) * DHW + s0 + xr] = vv;
        }
    }
}

// ---------------------------------------------------------------------------
// k_uv: fp32 depthwise 3x3x3 (replicate pad) -> l2norm over r -> dot Vp.
// D-INNERMOST LDS tile [4 rows][128 x][10 (8d+2 pad)]: one spatial tap fetches
// all 8 d-values via 4x ds_read_b64 (40B rows, 8B-aligned, gcd(10,32)=2 ->
// ~4-way aliasing) — 36 LDS reads/thread vs 72 scalar in the d-major layout.
// Same 648 FMA: a[d'] += v[clamp(d'-1+dk)]*U[dk][ky][kx][r] reproduces the
// original CONTRIB coverage incl. both replicate clamps. Vp prefetched into
// registers before the conv so its L2 latency hides under the FMAs.
// h stays fp32 (bf16-h failed the gate); UV written bf16 (post-norm, safe).
// ---------------------------------------------------------------------------
__global__ __launch_bounds__(256) void k_uv(const float* __restrict__ h,
                                            const float* __restrict__ Vp,
                                            const float* __restrict__ U_w,
                                            unsigned short* __restrict__ UVq)
{
    __shared__ float tile[4][Wd][10];   // 20 KB, rows y0-1..y0+2 (clamped)

    int blk = blockIdx.x;
    int yt  = blk & 63;
    int bc  = blk >> 6;                 // b*64 + c
    int b   = bc >> 6;
    int y0  = yt * 2;
    int t   = threadIdx.x;

    const float* hb = h + (size_t)bc * DHW;
#pragma unroll
    for (int rep = 0; rep < 4; ++rep) {   // 1024 float4 units, transposed write
        int idx = rep * 256 + t;
        int d   = idx >> 7;
        int rem = idx & 127;
        int lr  = rem >> 5;
        int x4  = (rem & 31) * 4;
        int zy  = y0 - 1 + lr;
        zy = zy < 0 ? 0 : (zy > Hd - 1 ? Hd - 1 : zy);
        floatx4 f = *(const floatx4*)(hb + d * HW + zy * Wd + x4);
#pragma unroll
        for (int j = 0; j < 4; ++j) tile[lr][x4 + j][d] = f[j];
    }
    __syncthreads();

    int xx = t & 127;
    int yr = t >> 7;
    int y  = y0 + yr;
    int xm = xx - 1; if (xm < 0) xm = 0;
    int xp = xx + 1; if (xp > Wd - 1) xp = Wd - 1;

    // Prefetch Vp (24 regs) — issued before the conv, consumed after.
    const float* vpb = Vp + (size_t)b * 3 * DHW + y * Wd + xx;
    float pv0[8], pv1[8], pv2[8];
#pragma unroll
    for (int d = 0; d < 8; ++d) {
        pv0[d] = vpb[(size_t)d * HW];
        pv1[d] = vpb[(size_t)DHW + d * HW];
        pv2[d] = vpb[(size_t)2 * DHW + d * HW];
    }

    float a0[8], a1[8], a2[8];
#pragma unroll
    for (int d = 0; d < 8; ++d) { a0[d] = 0.f; a1[d] = 0.f; a2[d] = 0.f; }

#pragma unroll
    for (int ky = 0; ky < 3; ++ky) {
#pragma unroll
        for (int kx = 0; kx < 3; ++kx) {
            int xcol = (kx == 0) ? xm : ((kx == 1) ? xx : xp);
            const float* rp = &tile[yr + ky][xcol][0];
            float v[8];
#pragma unroll
            for (int k2 = 0; k2 < 4; ++k2) {
                floatx2 p = *(const floatx2*)&rp[k2 * 2];
                v[k2 * 2] = p[0]; v[k2 * 2 + 1] = p[1];
            }
#pragma unroll
            for (int dp = 0; dp < 8; ++dp) {
#pragma unroll
                for (int dk = 0; dk < 3; ++dk) {
                    int ds = dp - 1 + dk;
                    ds = ds < 0 ? 0 : (ds > 7 ? 7 : ds);
                    const int kk = (((dk) * 3 + ky) * 3 + kx) * 3;
                    a0[dp] += v[ds] * U_w[kk + 0];
                    a1[dp] += v[ds] * U_w[kk + 1];
                    a2[dp] += v[ds] * U_w[kk + 2];
                }
            }
        }
    }

    unsigned short* uvb = UVq + (size_t)bc * DHW + y * Wd + xx;
#pragma unroll
    for (int d = 0; d < 8; ++d) {
        float nrm = sqrtf(a0[d] * a0[d] + a1[d] * a1[d] + a2[d] * a2[d]);
        float inv = 1.f / (1e-6f + nrm);
        float uv = (a0[d] * pv0[d] + a1[d] * pv1[d] + a2[d] * pv2[d]) * inv;
        uvb[(size_t)d * HW] = (unsigned short)f2bf(uv);
    }
}

// ---------------------------------------------------------------------------
// k_tailm: out = Wt[64x64] @ UV(bf16) via MFMA; W split (a*bh + a*bl).
// R5-verified staged version: bf16 X through LDS, Cb epilogue. LDS 33 KB.
// ---------------------------------------------------------------------------
__global__ __launch_bounds__(256) void k_tailm(const unsigned short* __restrict__ UVq,
                                               const short* __restrict__ Wth,
                                               const short* __restrict__ Wtl,
                                               float* __restrict__ out)
{
    __shared__ __align__(16) char smem[34 * 1024];
    short* Xh = (short*)smem;                    // 16 KB
    short* Bh = (short*)(smem + 16 * 1024);      // 8 KB
    short* Bl = (short*)(smem + 24 * 1024);      // 8 KB
    float* Cb = (float*)smem;                    // 64*132*4 = 33792 B

    int t  = threadIdx.x;
    int p0 = blockIdx.x * 128;
    int b  = p0 >> 17;
    int s0 = p0 & (DHW - 1);
    const unsigned short* uq = UVq + ((size_t)b * Cn) * DHW + s0;

    int pp = t & 127;
    int ho = t >> 7;
#pragma unroll
    for (int pass = 0; pass < 4; ++pass) {
        int in0 = pass * 16 + ho * 8;
        short8 vh;
#pragma unroll
        for (int j = 0; j < 8; ++j)
            vh[j] = (short)uq[(size_t)(in0 + j) * DHW + pp];
        int blk  = ((in0 >> 5) << 3) | (pp >> 4);
        int slot = (((in0 >> 3) & 3) << 4) | (pp & 15);
        *(short8*)&Xh[(blk * 64 + slot) * 8] = vh;
    }
#pragma unroll
    for (int pass = 0; pass < 2; ++pass) {   // 512 16B-units of Wt
        int unit = pass * 256 + t;
        int o    = unit & 63;
        int oc   = unit >> 6;
        int in0  = oc * 8;
        int blk  = ((o >> 4) << 1) | (in0 >> 5);
        int slot = (((in0 >> 3) & 3) << 4) | (o & 15);
        *(short8*)&Bh[(blk * 64 + slot) * 8] = *(const short8*)&Wth[o * 64 + in0];
        *(short8*)&Bl[(blk * 64 + slot) * 8] = *(const short8*)&Wtl[o * 64 + in0];
    }
    __syncthreads();

    int lane = t & 63;
    int w    = t >> 6;
    floatx4 acc[2][4];
#pragma unroll
    for (int mt = 0; mt < 2; ++mt)
#pragma unroll
        for (int nt = 0; nt < 4; ++nt) acc[mt][nt] = (floatx4)0.f;

    const short8* XhV = (const short8*)Xh;
    const short8* BhV = (const short8*)Bh;
    const short8* BlV = (const short8*)Bl;
#pragma unroll
    for (int ks = 0; ks < 2; ++ks) {
        short8 ah0 = XhV[(ks * 8 + w * 2 + 0) * 64 + lane];
        short8 ah1 = XhV[(ks * 8 + w * 2 + 1) * 64 + lane];
#pragma unroll
        for (int nt = 0; nt < 4; ++nt) {
            short8 bh = BhV[(nt * 2 + ks) * 64 + lane];
            short8 bl = BlV[(nt * 2 + ks) * 64 + lane];
            acc[0][nt] = __builtin_amdgcn_mfma_f32_16x16x32_bf16(ah0, bl, acc[0][nt], 0, 0, 0);
            acc[0][nt] = __builtin_amdgcn_mfma_f32_16x16x32_bf16(ah0, bh, acc[0][nt], 0, 0, 0);
            acc[1][nt] = __builtin_amdgcn_mfma_f32_16x16x32_bf16(ah1, bl, acc[1][nt], 0, 0, 0);
            acc[1][nt] = __builtin_amdgcn_mfma_f32_16x16x32_bf16(ah1, bh, acc[1][nt], 0, 0, 0);
        }
    }

    __syncthreads();
    int outc = lane & 15;
    int quad = lane >> 4;
#pragma unroll
    for (int mt = 0; mt < 2; ++mt)
#pragma unroll
        for (int nt = 0; nt < 4; ++nt) {
            int o   = nt * 16 + outc;
            int pos = w * 32 + mt * 16 + quad * 4;
            *(floatx4*)&Cb[o * 132 + pos] = acc[mt][nt];
        }
    __syncthreads();

    int xr = (t & 31) * 4;
    int ob = t >> 5;
#pragma unroll
    for (int pass = 0; pass < 8; ++pass) {
        int o = pass * 8 + ob;
        floatx4 vv = *(const floatx4*)&Cb[o * 132 + xr];
        *(floatx4*)&out[((size_t)(b * Cn + o)) * DHW + s0 + xr] = vv;
    }
}

extern "C" void kernel_launch(void* const* d_in, const int* in_sizes, int n_in,
                              void* d_out, int out_size, void* d_ws, size_t ws_size,
                              hipStream_t stream)
{
    const float* x      = (const float*)d_in[0];
    const float* head_w = (const float*)d_in[1];
    const float* tail_w = (const float*)d_in[2];
    const float* U_w    = (const float*)d_in[3];
    const float* V_w    = (const float*)d_in[4];
    float* out = (float*)d_out;

    // ws: h fp32 (64MB) | Vp fp32 (3MB) | UVq bf16 (32MB) | split weights
    float* h   = (float*)d_ws;
    float* Vp  = h + (size_t)NELEM;
    unsigned short* UVq = (unsigned short*)(Vp + (size_t)Bn * 3 * DHW);
    short* Whh = (short*)(UVq + (size_t)NELEM);
    short* Whl = Whh + 80 * 64;
    short* Wth = Whl + 80 * 64;
    short* Wtl = Wth + 64 * 64;

    k_prep<<<1, 256, 0, stream>>>(head_w, tail_w, V_w, Whh, Whl, Wth, Wtl);
    k_headm<<<NPOS / 128, 256, 0, stream>>>(x, Whh, Whl, h, Vp);
    k_uv<<<Bn * Cn * (Hd / 2), 256, 0, stream>>>(h, Vp, U_w, UVq);
    k_tailm<<<NPOS / 128, 256, 0, stream>>>(UVq, Wth, Wtl, out);
}

// Round 9
// 222.527 us; speedup vs baseline: 1.0378x; 1.0087x over previous
//
#include <hip/hip_runtime.h>

#define Bn   2
#define Cn   64
#define Dd   8
#define Hd   128
#define Wd   128
#define HW   16384
#define DHW  131072     // 2^17
#define NPOS 262144     // 2^18
#define NELEM 16777216

typedef __attribute__((ext_vector_type(8))) short short8;
typedef __attribute__((ext_vector_type(4))) float floatx4;
typedef __attribute__((ext_vector_type(4))) unsigned short ushort4v;

__device__ __forceinline__ short f2bf(float f) {
    union { float f; unsigned u; } v; v.f = f;
    unsigned r = (v.u + 0x7FFFu + ((v.u >> 16) & 1u)) >> 16;   // RNE
    return (short)r;
}
__device__ __forceinline__ float bf2f(short s) {
    union { unsigned u; float f; } v; v.u = ((unsigned)(unsigned short)s) << 16;
    return v.f;
}
// Cheap truncation split: hi = upper16(f), lo = trunc16(f - hi). ~4 VALU ops.
// Pair error ~2^-17 relative — fp32-class for K=64 GEMMs.
__device__ __forceinline__ void split2(float f, short& hi, short& lo) {
    union { float f; unsigned u; } a; a.f = f;
    unsigned hu = a.u & 0xFFFF0000u;
    hi = (short)(hu >> 16);
    union { unsigned u; float f; } hb; hb.u = hu;
    union { float f; unsigned u; } lb; lb.f = f - hb.f;
    lo = (short)(lb.u >> 16);
}

// ---------------------------------------------------------------------------
// k_prep: split-bf16 weights. Wh{h,l}[80][64]: rows 0..63 = head_w,
// rows 64..66 = V^T @ head_w (folds Vp), rows 67..79 = 0. Wt{h,l}[64][64].
// ---------------------------------------------------------------------------
__global__ __launch_bounds__(256) void k_prep(const float* __restrict__ head_w,
                                              const float* __restrict__ tail_w,
                                              const float* __restrict__ V_w,
                                              short* __restrict__ Whh, short* __restrict__ Whl,
                                              short* __restrict__ Wth, short* __restrict__ Wtl)
{
    int t = threadIdx.x;
#pragma unroll
    for (int rep = 0; rep < 16; ++rep) {
        int idx = rep * 256 + t;            // 4096
        short hh, hl;
        split2(head_w[idx], hh, hl);
        Whh[idx] = hh; Whl[idx] = hl;
        split2(tail_w[idx], hh, hl);
        Wth[idx] = hh; Wtl[idx] = hl;
    }
    if (t < 192) {                          // VW[r][i] = sum_c V[c][r]*W[c][i]
        int r = t >> 6, i = t & 63;
        float s = 0.f;
        for (int cc = 0; cc < 64; ++cc) s += V_w[cc * 3 + r] * head_w[cc * 64 + i];
        short hh, hl;
        split2(s, hh, hl);
        Whh[(64 + r) * 64 + i] = hh;
        Whl[(64 + r) * 64 + i] = hl;
    }
#pragma unroll
    for (int rep = 0; rep < 4; ++rep) {     // zero rows 67..79 (832 entries)
        int idx = rep * 256 + t;
        if (idx < 832) { Whh[67 * 64 + idx] = 0; Whl[67 * 64 + idx] = 0; }
    }
}

// ---------------------------------------------------------------------------
// k_headm: [h | Vp] = Wh[80x64] @ x via split-bf16 MFMA (fp32-equivalent,
// 3-product: al*bh + ah*bl + ah*bh). OCCUPANCY RESTRUCTURE (36 KB LDS ->
// 4 blocks/CU, was 52 KB -> 3):
//  - Split-K X staging: ch 0..31 staged in 8+8 KB; ch 32..63 prefetched to
//    registers BEFORE the first barrier (HBM latency hides under ks=0 MFMAs,
//    T14 issue-early/write-late), ds_written after ks=0 completes.
//  - Split-N Cb epilogue: nt 0..2 (25.3 KB) then nt 3..4 (16.9 KB).
// Same slot maps with the ks bit dropped on both sides; numerics identical.
// ---------------------------------------------------------------------------
__global__ __launch_bounds__(256) void k_headm(const float* __restrict__ x,
                                               const short* __restrict__ Whh,
                                               const short* __restrict__ Whl,
                                               float* __restrict__ h,
                                               float* __restrict__ Vp)
{
    __shared__ __align__(16) char smem[36 * 1024];
    short* Xh = (short*)smem;                    // 8 KB (one K-half)
    short* Xl = (short*)(smem + 8 * 1024);       // 8 KB
    short* Bh = (short*)(smem + 16 * 1024);      // 10 KB
    short* Bl = (short*)(smem + 26 * 1024);      // 10 KB
    float* Cb = (float*)smem;                    // phase A: 48*132*4 = 25344 B

    int t  = threadIdx.x;
    int p0 = blockIdx.x * 128;
    int b  = p0 >> 17;
    int s0 = p0 & (DHW - 1);
    const float* xb = x + ((size_t)b * Cn) * DHW + s0;

    int pp = t & 127;
    int ho = t >> 7;

    // Prefetch K-half 1 (ch 32..63) into registers — issued before barrier 1.
    float xreg[16];
#pragma unroll
    for (int pass = 0; pass < 2; ++pass) {
        int in0 = 32 + pass * 16 + ho * 8;
#pragma unroll
        for (int j = 0; j < 8; ++j)
            xreg[pass * 8 + j] = xb[(size_t)(in0 + j) * DHW + pp];
    }
    // Stage K-half 0 (ch 0..31).
#pragma unroll
    for (int pass = 0; pass < 2; ++pass) {
        int in0 = pass * 16 + ho * 8;           // 0..31
        short8 vh, vl;
#pragma unroll
        for (int j = 0; j < 8; ++j) {
            short hh, hl;
            split2(xb[(size_t)(in0 + j) * DHW + pp], hh, hl);
            vh[j] = hh; vl[j] = hl;
        }
        int blk  = pp >> 4;
        int slot = (((in0 >> 3) & 3) << 4) | (pp & 15);
        *(short8*)&Xh[(blk * 64 + slot) * 8] = vh;
        *(short8*)&Xl[(blk * 64 + slot) * 8] = vl;
    }
    // Stage B (all 80 outputs x 64 ch).
#pragma unroll
    for (int pass = 0; pass < 3; ++pass) {   // 640 16B-units of Wh
        int unit = pass * 256 + t;
        if (unit < 640) {
            int o   = unit - (unit / 80) * 80;
            int oc  = unit / 80;
            int in0 = oc * 8;
            int blk  = ((o >> 4) << 1) | (in0 >> 5);
            int slot = (((in0 >> 3) & 3) << 4) | (o & 15);
            *(short8*)&Bh[(blk * 64 + slot) * 8] = *(const short8*)&Whh[o * 64 + in0];
            *(short8*)&Bl[(blk * 64 + slot) * 8] = *(const short8*)&Whl[o * 64 + in0];
        }
    }
    __syncthreads();

    int lane = t & 63;
    int w    = t >> 6;
    floatx4 acc[2][5];
#pragma unroll
    for (int mt = 0; mt < 2; ++mt)
#pragma unroll
        for (int nt = 0; nt < 5; ++nt) acc[mt][nt] = (floatx4)0.f;

    const short8* XhV = (const short8*)Xh;
    const short8* XlV = (const short8*)Xl;
    const short8* BhV = (const short8*)Bh;
    const short8* BlV = (const short8*)Bl;
    {   // ks = 0
        short8 ah0 = XhV[(w * 2 + 0) * 64 + lane];
        short8 ah1 = XhV[(w * 2 + 1) * 64 + lane];
        short8 al0 = XlV[(w * 2 + 0) * 64 + lane];
        short8 al1 = XlV[(w * 2 + 1) * 64 + lane];
#pragma unroll
        for (int nt = 0; nt < 5; ++nt) {
            short8 bh = BhV[(nt * 2 + 0) * 64 + lane];
            short8 bl = BlV[(nt * 2 + 0) * 64 + lane];
            acc[0][nt] = __builtin_amdgcn_mfma_f32_16x16x32_bf16(al0, bh, acc[0][nt], 0, 0, 0);
            acc[0][nt] = __builtin_amdgcn_mfma_f32_16x16x32_bf16(ah0, bl, acc[0][nt], 0, 0, 0);
            acc[0][nt] = __builtin_amdgcn_mfma_f32_16x16x32_bf16(ah0, bh, acc[0][nt], 0, 0, 0);
            acc[1][nt] = __builtin_amdgcn_mfma_f32_16x16x32_bf16(al1, bh, acc[1][nt], 0, 0, 0);
            acc[1][nt] = __builtin_amdgcn_mfma_f32_16x16x32_bf16(ah1, bl, acc[1][nt], 0, 0, 0);
            acc[1][nt] = __builtin_amdgcn_mfma_f32_16x16x32_bf16(ah1, bh, acc[1][nt], 0, 0, 0);
        }
    }
    __syncthreads();                          // all waves done reading X half-0

    // Restage X with ch 32..63 from registers (same slot map, ks bit dropped).
#pragma unroll
    for (int pass = 0; pass < 2; ++pass) {
        int in0 = pass * 16 + ho * 8;
        short8 vh, vl;
#pragma unroll
        for (int j = 0; j < 8; ++j) {
            short hh, hl;
            split2(xreg[pass * 8 + j], hh, hl);
            vh[j] = hh; vl[j] = hl;
        }
        int blk  = pp >> 4;
        int slot = (((in0 >> 3) & 3) << 4) | (pp & 15);
        *(short8*)&Xh[(blk * 64 + slot) * 8] = vh;
        *(short8*)&Xl[(blk * 64 + slot) * 8] = vl;
    }
    __syncthreads();

    {   // ks = 1
        short8 ah0 = XhV[(w * 2 + 0) * 64 + lane];
        short8 ah1 = XhV[(w * 2 + 1) * 64 + lane];
        short8 al0 = XlV[(w * 2 + 0) * 64 + lane];
        short8 al1 = XlV[(w * 2 + 1) * 64 + lane];
#pragma unroll
        for (int nt = 0; nt < 5; ++nt) {
            short8 bh = BhV[(nt * 2 + 1) * 64 + lane];
            short8 bl = BlV[(nt * 2 + 1) * 64 + lane];
            acc[0][nt] = __builtin_amdgcn_mfma_f32_16x16x32_bf16(al0, bh, acc[0][nt], 0, 0, 0);
            acc[0][nt] = __builtin_amdgcn_mfma_f32_16x16x32_bf16(ah0, bl, acc[0][nt], 0, 0, 0);
            acc[0][nt] = __builtin_amdgcn_mfma_f32_16x16x32_bf16(ah0, bh, acc[0][nt], 0, 0, 0);
            acc[1][nt] = __builtin_amdgcn_mfma_f32_16x16x32_bf16(al1, bh, acc[1][nt], 0, 0, 0);
            acc[1][nt] = __builtin_amdgcn_mfma_f32_16x16x32_bf16(ah1, bl, acc[1][nt], 0, 0, 0);
            acc[1][nt] = __builtin_amdgcn_mfma_f32_16x16x32_bf16(ah1, bh, acc[1][nt], 0, 0, 0);
        }
    }
    __syncthreads();                          // MFMA done; X/B free for Cb

    int outc = lane & 15;
    int quad = lane >> 4;
    int xr = (t & 31) * 4;                    // 0..124
    int ob = t >> 5;                          // 0..7

    // Epilogue phase A: outputs o = 0..47 (nt 0..2).
#pragma unroll
    for (int mt = 0; mt < 2; ++mt)
#pragma unroll
        for (int nt = 0; nt < 3; ++nt) {
            int o   = nt * 16 + outc;
            int pos = w * 32 + mt * 16 + quad * 4;
            *(floatx4*)&Cb[o * 132 + pos] = acc[mt][nt];
        }
    __syncthreads();
#pragma unroll
    for (int pass = 0; pass < 6; ++pass) {
        int o = pass * 8 + ob;                // 0..47, all h
        floatx4 vv = *(const floatx4*)&Cb[o * 132 + xr];
        *(floatx4*)&h[((size_t)(b * Cn + o)) * DHW + s0 + xr] = vv;
    }
    __syncthreads();

    // Epilogue phase B: outputs o = 48..79 (nt 3..4) at Cb rows o-48.
#pragma unroll
    for (int mt = 0; mt < 2; ++mt)
#pragma unroll
        for (int nt = 3; nt < 5; ++nt) {
            int o   = nt * 16 + outc;
            int pos = w * 32 + mt * 16 + quad * 4;
            *(floatx4*)&Cb[(o - 48) * 132 + pos] = acc[mt][nt];
        }
    __syncthreads();
#pragma unroll
    for (int pass = 0; pass < 4; ++pass) {
        int op = pass * 8 + ob;               // 0..31
        int o  = op + 48;                     // 48..79
        floatx4 vv = *(const floatx4*)&Cb[op * 132 + xr];
        if (o < 64) {
            *(floatx4*)&h[((size_t)(b * Cn + o)) * DHW + s0 + xr] = vv;
        } else if (o < 67) {
            *(floatx4*)&Vp[((size_t)(b * 3 + (o - 64))) * DHW + s0 + xr] = vv;
        }
    }
}

// ---------------------------------------------------------------------------
// k_uv: fp32 depthwise 3x3x3 (replicate pad) -> l2norm over r -> dot Vp.
// R5-verified form — 3 restructures (x4-vec, d-split, d-innermost) all lost
// to it; d-major tile + slice-major register schedule is the local optimum
// (61.6us, VALUBusy ~90%, 0 conflicts, VGPR 40, occ 54%). KEEP EXACT.
// h fp32 (bf16-h failed gate); UV written bf16 (post-norm, verified safe).
// ---------------------------------------------------------------------------
__global__ __launch_bounds__(256) void k_uv(const float* __restrict__ h,
                                            const float* __restrict__ Vp,
                                            const float* __restrict__ U_w,
                                            unsigned short* __restrict__ UVq)
{
    __shared__ float tile[Dd][4][Wd];   // 16 KB

    int blk = blockIdx.x;
    int yt  = blk & 63;
    int bc  = blk >> 6;                 // b*64 + c
    int b   = bc >> 6;
    int y0  = yt * 2;
    int t   = threadIdx.x;

    const float* hb = h + (size_t)bc * DHW;
#pragma unroll
    for (int rep = 0; rep < 4; ++rep) {   // 1024 float4 units
        int idx = rep * 256 + t;
        int d   = idx >> 7;
        int rem = idx & 127;
        int yr  = rem >> 5;
        int x4  = (rem & 31) * 4;
        int zy  = y0 - 1 + yr;
        zy = zy < 0 ? 0 : (zy > Hd - 1 ? Hd - 1 : zy);
        *(floatx4*)&tile[d][yr][x4] = *(const floatx4*)(hb + d * HW + zy * Wd + x4);
    }
    __syncthreads();

    int xx = t & 127;
    int yr = t >> 7;
    int y  = y0 + yr;
    int xm = xx - 1; if (xm < 0) xm = 0;
    int xp = xx + 1; if (xp > Wd - 1) xp = Wd - 1;

    float a0[8], a1[8], a2[8];
#pragma unroll
    for (int d = 0; d < 8; ++d) { a0[d] = 0.f; a1[d] = 0.f; a2[d] = 0.f; }

#define CONTRIB(dd, dk)                                                   \
    {                                                                     \
        _Pragma("unroll")                                                 \
        for (int kh = 0; kh < 3; ++kh) {                                  \
            _Pragma("unroll")                                             \
            for (int kw = 0; kw < 3; ++kw) {                              \
                const int kk = (((dk) * 3 + kh) * 3 + kw) * 3;            \
                a0[dd] += v[kh][kw] * U_w[kk + 0];                        \
                a1[dd] += v[kh][kw] * U_w[kk + 1];                        \
                a2[dd] += v[kh][kw] * U_w[kk + 2];                        \
            }                                                             \
        }                                                                 \
    }

#pragma unroll
    for (int sl = 0; sl < 8; ++sl) {
        float v[3][3];
#pragma unroll
        for (int kh = 0; kh < 3; ++kh) {
            const float* row = &tile[sl][yr + kh][0];
            v[kh][0] = row[xm]; v[kh][1] = row[xx]; v[kh][2] = row[xp];
        }
        CONTRIB(sl, 1);                         // dk=1 -> d = sl
        if (sl == 0) CONTRIB(0, 0);             // replicate clamp low
        if (sl < 7)  CONTRIB(sl + 1, 0);        // dk=0 -> d = sl+1
        if (sl > 0)  CONTRIB(sl - 1, 2);        // dk=2 -> d = sl-1
        if (sl == 7) CONTRIB(7, 2);             // replicate clamp high
    }
#undef CONTRIB

    const float* vpb    = Vp + (size_t)b * 3 * DHW + y * Wd + xx;
    unsigned short* uvb = UVq + (size_t)bc * DHW + y * Wd + xx;
#pragma unroll
    for (int d = 0; d < 8; ++d) {
        float nrm = sqrtf(a0[d] * a0[d] + a1[d] * a1[d] + a2[d] * a2[d]);
        float inv = 1.f / (1e-6f + nrm);
        float uv = (a0[d] * vpb[(size_t)d * HW]
                  + a1[d] * vpb[(size_t)DHW + d * HW]
                  + a2[d] * vpb[(size_t)2 * DHW + d * HW]) * inv;
        uvb[(size_t)d * HW] = (unsigned short)f2bf(uv);
    }
}

// ---------------------------------------------------------------------------
// k_tailm: out = Wt[64x64] @ UV(bf16) via MFMA; W split (a*bh + a*bl).
// R5-verified staged version: bf16 X through LDS, Cb epilogue. LDS 34 KB.
// ---------------------------------------------------------------------------
__global__ __launch_bounds__(256) void k_tailm(const unsigned short* __restrict__ UVq,
                                               const short* __restrict__ Wth,
                                               const short* __restrict__ Wtl,
                                               float* __restrict__ out)
{
    __shared__ __align__(16) char smem[34 * 1024];
    short* Xh = (short*)smem;                    // 16 KB
    short* Bh = (short*)(smem + 16 * 1024);      // 8 KB
    short* Bl = (short*)(smem + 24 * 1024);      // 8 KB
    float* Cb = (float*)smem;                    // 64*132*4 = 33792 B

    int t  = threadIdx.x;
    int p0 = blockIdx.x * 128;
    int b  = p0 >> 17;
    int s0 = p0 & (DHW - 1);
    const unsigned short* uq = UVq + ((size_t)b * Cn) * DHW + s0;

    int pp = t & 127;
    int ho = t >> 7;
#pragma unroll
    for (int pass = 0; pass < 4; ++pass) {
        int in0 = pass * 16 + ho * 8;
        short8 vh;
#pragma unroll
        for (int j = 0; j < 8; ++j)
            vh[j] = (short)uq[(size_t)(in0 + j) * DHW + pp];
        int blk  = ((in0 >> 5) << 3) | (pp >> 4);
        int slot = (((in0 >> 3) & 3) << 4) | (pp & 15);
        *(short8*)&Xh[(blk * 64 + slot) * 8] = vh;
    }
#pragma unroll
    for (int pass = 0; pass < 2; ++pass) {   // 512 16B-units of Wt
        int unit = pass * 256 + t;
        int o    = unit & 63;
        int oc   = unit >> 6;
        int in0  = oc * 8;
        int blk  = ((o >> 4) << 1) | (in0 >> 5);
        int slot = (((in0 >> 3) & 3) << 4) | (o & 15);
        *(short8*)&Bh[(blk * 64 + slot) * 8] = *(const short8*)&Wth[o * 64 + in0];
        *(short8*)&Bl[(blk * 64 + slot) * 8] = *(const short8*)&Wtl[o * 64 + in0];
    }
    __syncthreads();

    int lane = t & 63;
    int w    = t >> 6;
    floatx4 acc[2][4];
#pragma unroll
    for (int mt = 0; mt < 2; ++mt)
#pragma unroll
        for (int nt = 0; nt < 4; ++nt) acc[mt][nt] = (floatx4)0.f;

    const short8* XhV = (const short8*)Xh;
    const short8* BhV = (const short8*)Bh;
    const short8* BlV = (const short8*)Bl;
#pragma unroll
    for (int ks = 0; ks < 2; ++ks) {
        short8 ah0 = XhV[(ks * 8 + w * 2 + 0) * 64 + lane];
        short8 ah1 = XhV[(ks * 8 + w * 2 + 1) * 64 + lane];
#pragma unroll
        for (int nt = 0; nt < 4; ++nt) {
            short8 bh = BhV[(nt * 2 + ks) * 64 + lane];
            short8 bl = BlV[(nt * 2 + ks) * 64 + lane];
            acc[0][nt] = __builtin_amdgcn_mfma_f32_16x16x32_bf16(ah0, bl, acc[0][nt], 0, 0, 0);
            acc[0][nt] = __builtin_amdgcn_mfma_f32_16x16x32_bf16(ah0, bh, acc[0][nt], 0, 0, 0);
            acc[1][nt] = __builtin_amdgcn_mfma_f32_16x16x32_bf16(ah1, bl, acc[1][nt], 0, 0, 0);
            acc[1][nt] = __builtin_amdgcn_mfma_f32_16x16x32_bf16(ah1, bh, acc[1][nt], 0, 0, 0);
        }
    }

    __syncthreads();
    int outc = lane & 15;
    int quad = lane >> 4;
#pragma unroll
    for (int mt = 0; mt < 2; ++mt)
#pragma unroll
        for (int nt = 0; nt < 4; ++nt) {
            int o   = nt * 16 + outc;
            int pos = w * 32 + mt * 16 + quad * 4;
            *(floatx4*)&Cb[o * 132 + pos] = acc[mt][nt];
        }
    __syncthreads();

    int xr = (t & 31) * 4;
    int ob = t >> 5;
#pragma unroll
    for (int pass = 0; pass < 8; ++pass) {
        int o = pass * 8 + ob;
        floatx4 vv = *(const floatx4*)&Cb[o * 132 + xr];
        *(floatx4*)&out[((size_t)(b * Cn + o)) * DHW + s0 + xr] = vv;
    }
}

extern "C" void kernel_launch(void* const* d_in, const int* in_sizes, int n_in,
                              void* d_out, int out_size, void* d_ws, size_t ws_size,
                              hipStream_t stream)
{
    const float* x      = (const float*)d_in[0];
    const float* head_w = (const float*)d_in[1];
    const float* tail_w = (const float*)d_in[2];
    const float* U_w    = (const float*)d_in[3];
    const float* V_w    = (const float*)d_in[4];
    float* out = (float*)d_out;

    // ws: h fp32 (64MB) | Vp fp32 (3MB) | UVq bf16 (32MB) | split weights
    float* h   = (float*)d_ws;
    float* Vp  = h + (size_t)NELEM;
    unsigned short* UVq = (unsigned short*)(Vp + (size_t)Bn * 3 * DHW);
    short* Whh = (short*)(UVq + (size_t)NELEM);
    short* Whl = Whh + 80 * 64;
    short* Wth = Whl + 80 * 64;
    short* Wtl = Wth + 64 * 64;

    k_prep<<<1, 256, 0, stream>>>(head_w, tail_w, V_w, Whh, Whl, Wth, Wtl);
    k_headm<<<NPOS / 128, 256, 0, stream>>>(x, Whh, Whl, h, Vp);
    k_uv<<<Bn * Cn * (Hd / 2), 256, 0, stream>>>(h, Vp, U_w, UVq);
    k_tailm<<<NPOS / 128, 256, 0, stream>>>(UVq, Wth, Wtl, out);
}

// Round 10
// 219.822 us; speedup vs baseline: 1.0506x; 1.0123x over previous
//
#include <hip/hip_runtime.h>

#define Bn   2
#define Cn   64
#define Dd   8
#define Hd   128
#define Wd   128
#define HW   16384
#define DHW  131072     // 2^17
#define NPOS 262144     // 2^18
#define NELEM 16777216

typedef __attribute__((ext_vector_type(8))) short short8;
typedef __attribute__((ext_vector_type(4))) float floatx4;
typedef __attribute__((ext_vector_type(4))) unsigned short ushort4v;

__device__ __forceinline__ short f2bf(float f) {
    union { float f; unsigned u; } v; v.f = f;
    unsigned r = (v.u + 0x7FFFu + ((v.u >> 16) & 1u)) >> 16;   // RNE
    return (short)r;
}
__device__ __forceinline__ float bf2f(short s) {
    union { unsigned u; float f; } v; v.u = ((unsigned)(unsigned short)s) << 16;
    return v.f;
}
// Cheap truncation split: hi = upper16(f), lo = trunc16(f - hi). ~4 VALU ops.
// Pair error ~2^-17 relative — fp32-class for K=64 GEMMs.
__device__ __forceinline__ void split2(float f, short& hi, short& lo) {
    union { float f; unsigned u; } a; a.f = f;
    unsigned hu = a.u & 0xFFFF0000u;
    hi = (short)(hu >> 16);
    union { unsigned u; float f; } hb; hb.u = hu;
    union { float f; unsigned u; } lb; lb.f = f - hb.f;
    lo = (short)(lb.u >> 16);
}

// ---------------------------------------------------------------------------
// k_prep: split-bf16 weights. Wh{h,l}[80][64]: rows 0..63 = head_w,
// rows 64..66 = V^T @ head_w (folds Vp), rows 67..79 = 0. Wt{h,l}[64][64].
// ---------------------------------------------------------------------------
__global__ __launch_bounds__(256) void k_prep(const float* __restrict__ head_w,
                                              const float* __restrict__ tail_w,
                                              const float* __restrict__ V_w,
                                              short* __restrict__ Whh, short* __restrict__ Whl,
                                              short* __restrict__ Wth, short* __restrict__ Wtl)
{
    int t = threadIdx.x;
#pragma unroll
    for (int rep = 0; rep < 16; ++rep) {
        int idx = rep * 256 + t;            // 4096
        short hh, hl;
        split2(head_w[idx], hh, hl);
        Whh[idx] = hh; Whl[idx] = hl;
        split2(tail_w[idx], hh, hl);
        Wth[idx] = hh; Wtl[idx] = hl;
    }
    if (t < 192) {                          // VW[r][i] = sum_c V[c][r]*W[c][i]
        int r = t >> 6, i = t & 63;
        float s = 0.f;
        for (int cc = 0; cc < 64; ++cc) s += V_w[cc * 3 + r] * head_w[cc * 64 + i];
        short hh, hl;
        split2(s, hh, hl);
        Whh[(64 + r) * 64 + i] = hh;
        Whl[(64 + r) * 64 + i] = hl;
    }
#pragma unroll
    for (int rep = 0; rep < 4; ++rep) {     // zero rows 67..79 (832 entries)
        int idx = rep * 256 + t;
        if (idx < 832) { Whh[67 * 64 + idx] = 0; Whl[67 * 64 + idx] = 0; }
    }
}

// ---------------------------------------------------------------------------
// k_headm: [h | Vp] = Wh[80x64] @ x via split-bf16 MFMA (fp32-equivalent).
// 3-product split: ah*bh + ah*bl + al*bh (al*bl ~2^-16 rel, dropped).
// R5-verified staged version (measured-best, 220.1us wall): X through LDS
// (256B-contiguous loads), Cb epilogue transpose (512B-contiguous stores).
// R7 direct-fragment (-LDS) and R9 split-K (+occupancy, +barriers) both
// failed to beat this — the LDS bounces buy access granularity; keep.
// ---------------------------------------------------------------------------
__global__ __launch_bounds__(256) void k_headm(const float* __restrict__ x,
                                               const short* __restrict__ Whh,
                                               const short* __restrict__ Whl,
                                               float* __restrict__ h,
                                               float* __restrict__ Vp)
{
    __shared__ __align__(16) char smem[52 * 1024];
    short* Xh = (short*)smem;                    // 16 KB
    short* Xl = (short*)(smem + 16 * 1024);      // 16 KB
    short* Bh = (short*)(smem + 32 * 1024);      // 10 KB
    short* Bl = (short*)(smem + 42 * 1024);      // 10 KB
    float* Cb = (float*)smem;                    // epilogue: 80*132*4 = 42240 B

    int t  = threadIdx.x;
    int p0 = blockIdx.x * 128;
    int b  = p0 >> 17;
    int s0 = p0 & (DHW - 1);
    const float* xb = x + ((size_t)b * Cn) * DHW + s0;

    int pp = t & 127;
    int ho = t >> 7;
#pragma unroll
    for (int pass = 0; pass < 4; ++pass) {
        int in0 = pass * 16 + ho * 8;
        short8 vh, vl;
#pragma unroll
        for (int j = 0; j < 8; ++j) {
            short hh, hl;
            split2(xb[(size_t)(in0 + j) * DHW + pp], hh, hl);
            vh[j] = hh; vl[j] = hl;
        }
        int blk  = ((in0 >> 5) << 3) | (pp >> 4);
        int slot = (((in0 >> 3) & 3) << 4) | (pp & 15);
        *(short8*)&Xh[(blk * 64 + slot) * 8] = vh;
        *(short8*)&Xl[(blk * 64 + slot) * 8] = vl;
    }
#pragma unroll
    for (int pass = 0; pass < 3; ++pass) {   // 640 16B-units of Wh
        int unit = pass * 256 + t;
        if (unit < 640) {
            int o   = unit - (unit / 80) * 80;
            int oc  = unit / 80;
            int in0 = oc * 8;
            int blk  = ((o >> 4) << 1) | (in0 >> 5);
            int slot = (((in0 >> 3) & 3) << 4) | (o & 15);
            *(short8*)&Bh[(blk * 64 + slot) * 8] = *(const short8*)&Whh[o * 64 + in0];
            *(short8*)&Bl[(blk * 64 + slot) * 8] = *(const short8*)&Whl[o * 64 + in0];
        }
    }
    __syncthreads();

    int lane = t & 63;
    int w    = t >> 6;
    floatx4 acc[2][5];
#pragma unroll
    for (int mt = 0; mt < 2; ++mt)
#pragma unroll
        for (int nt = 0; nt < 5; ++nt) acc[mt][nt] = (floatx4)0.f;

    const short8* XhV = (const short8*)Xh;
    const short8* XlV = (const short8*)Xl;
    const short8* BhV = (const short8*)Bh;
    const short8* BlV = (const short8*)Bl;
#pragma unroll
    for (int ks = 0; ks < 2; ++ks) {
        short8 ah0 = XhV[(ks * 8 + w * 2 + 0) * 64 + lane];
        short8 ah1 = XhV[(ks * 8 + w * 2 + 1) * 64 + lane];
        short8 al0 = XlV[(ks * 8 + w * 2 + 0) * 64 + lane];
        short8 al1 = XlV[(ks * 8 + w * 2 + 1) * 64 + lane];
#pragma unroll
        for (int nt = 0; nt < 5; ++nt) {
            short8 bh = BhV[(nt * 2 + ks) * 64 + lane];
            short8 bl = BlV[(nt * 2 + ks) * 64 + lane];
            acc[0][nt] = __builtin_amdgcn_mfma_f32_16x16x32_bf16(al0, bh, acc[0][nt], 0, 0, 0);
            acc[0][nt] = __builtin_amdgcn_mfma_f32_16x16x32_bf16(ah0, bl, acc[0][nt], 0, 0, 0);
            acc[0][nt] = __builtin_amdgcn_mfma_f32_16x16x32_bf16(ah0, bh, acc[0][nt], 0, 0, 0);
            acc[1][nt] = __builtin_amdgcn_mfma_f32_16x16x32_bf16(al1, bh, acc[1][nt], 0, 0, 0);
            acc[1][nt] = __builtin_amdgcn_mfma_f32_16x16x32_bf16(ah1, bl, acc[1][nt], 0, 0, 0);
            acc[1][nt] = __builtin_amdgcn_mfma_f32_16x16x32_bf16(ah1, bh, acc[1][nt], 0, 0, 0);
        }
    }

    __syncthreads();                        // frag reads done; reuse LDS as Cb
    int outc = lane & 15;
    int quad = lane >> 4;
#pragma unroll
    for (int mt = 0; mt < 2; ++mt)
#pragma unroll
        for (int nt = 0; nt < 5; ++nt) {
            int o   = nt * 16 + outc;
            int pos = w * 32 + mt * 16 + quad * 4;
            *(floatx4*)&Cb[o * 132 + pos] = acc[mt][nt];
        }
    __syncthreads();

    int xr = (t & 31) * 4;                  // 0..124
    int ob = t >> 5;                        // 0..7
#pragma unroll
    for (int pass = 0; pass < 9; ++pass) {
        int o = pass * 8 + ob;
        floatx4 vv = *(const floatx4*)&Cb[o * 132 + xr];
        if (o < 64) {
            *(floatx4*)&h[((size_t)(b * Cn + o)) * DHW + s0 + xr] = vv;
        } else if (o < 67) {
            *(floatx4*)&Vp[((size_t)(b * 3 + (o - 64))) * DHW + s0 + xr] = vv;
        }
    }
}

// ---------------------------------------------------------------------------
// k_uv: fp32 depthwise 3x3x3 (replicate pad) -> l2norm over r -> dot Vp.
// R5-verified form — 3 restructures (x4-vec, d-split, d-innermost) all lost
// to it; d-major tile + slice-major register schedule is the local optimum
// (~62us, VALUBusy ~90%, 0 conflicts, VGPR 40, occ 54%). KEEP EXACT.
// h fp32 (bf16-h failed gate); UV written bf16 (post-norm, verified safe).
// ---------------------------------------------------------------------------
__global__ __launch_bounds__(256) void k_uv(const float* __restrict__ h,
                                            const float* __restrict__ Vp,
                                            const float* __restrict__ U_w,
                                            unsigned short* __restrict__ UVq)
{
    __shared__ float tile[Dd][4][Wd];   // 16 KB

    int blk = blockIdx.x;
    int yt  = blk & 63;
    int bc  = blk >> 6;                 // b*64 + c
    int b   = bc >> 6;
    int y0  = yt * 2;
    int t   = threadIdx.x;

    const float* hb = h + (size_t)bc * DHW;
#pragma unroll
    for (int rep = 0; rep < 4; ++rep) {   // 1024 float4 units
        int idx = rep * 256 + t;
        int d   = idx >> 7;
        int rem = idx & 127;
        int yr  = rem >> 5;
        int x4  = (rem & 31) * 4;
        int zy  = y0 - 1 + yr;
        zy = zy < 0 ? 0 : (zy > Hd - 1 ? Hd - 1 : zy);
        *(floatx4*)&tile[d][yr][x4] = *(const floatx4*)(hb + d * HW + zy * Wd + x4);
    }
    __syncthreads();

    int xx = t & 127;
    int yr = t >> 7;
    int y  = y0 + yr;
    int xm = xx - 1; if (xm < 0) xm = 0;
    int xp = xx + 1; if (xp > Wd - 1) xp = Wd - 1;

    float a0[8], a1[8], a2[8];
#pragma unroll
    for (int d = 0; d < 8; ++d) { a0[d] = 0.f; a1[d] = 0.f; a2[d] = 0.f; }

#define CONTRIB(dd, dk)                                                   \
    {                                                                     \
        _Pragma("unroll")                                                 \
        for (int kh = 0; kh < 3; ++kh) {                                  \
            _Pragma("unroll")                                             \
            for (int kw = 0; kw < 3; ++kw) {                              \
                const int kk = (((dk) * 3 + kh) * 3 + kw) * 3;            \
                a0[dd] += v[kh][kw] * U_w[kk + 0];                        \
                a1[dd] += v[kh][kw] * U_w[kk + 1];                        \
                a2[dd] += v[kh][kw] * U_w[kk + 2];                        \
            }                                                             \
        }                                                                 \
    }

#pragma unroll
    for (int sl = 0; sl < 8; ++sl) {
        float v[3][3];
#pragma unroll
        for (int kh = 0; kh < 3; ++kh) {
            const float* row = &tile[sl][yr + kh][0];
            v[kh][0] = row[xm]; v[kh][1] = row[xx]; v[kh][2] = row[xp];
        }
        CONTRIB(sl, 1);                         // dk=1 -> d = sl
        if (sl == 0) CONTRIB(0, 0);             // replicate clamp low
        if (sl < 7)  CONTRIB(sl + 1, 0);        // dk=0 -> d = sl+1
        if (sl > 0)  CONTRIB(sl - 1, 2);        // dk=2 -> d = sl-1
        if (sl == 7) CONTRIB(7, 2);             // replicate clamp high
    }
#undef CONTRIB

    const float* vpb    = Vp + (size_t)b * 3 * DHW + y * Wd + xx;
    unsigned short* uvb = UVq + (size_t)bc * DHW + y * Wd + xx;
#pragma unroll
    for (int d = 0; d < 8; ++d) {
        float nrm = sqrtf(a0[d] * a0[d] + a1[d] * a1[d] + a2[d] * a2[d]);
        float inv = 1.f / (1e-6f + nrm);
        float uv = (a0[d] * vpb[(size_t)d * HW]
                  + a1[d] * vpb[(size_t)DHW + d * HW]
                  + a2[d] * vpb[(size_t)2 * DHW + d * HW]) * inv;
        uvb[(size_t)d * HW] = (unsigned short)f2bf(uv);
    }
}

// ---------------------------------------------------------------------------
// k_tailm: out = Wt[64x64] @ UV(bf16) via MFMA; W split (a*bh + a*bl).
// R5-verified staged version: bf16 X through LDS, Cb epilogue. LDS 34 KB.
// ---------------------------------------------------------------------------
__global__ __launch_bounds__(256) void k_tailm(const unsigned short* __restrict__ UVq,
                                               const short* __restrict__ Wth,
                                               const short* __restrict__ Wtl,
                                               float* __restrict__ out)
{
    __shared__ __align__(16) char smem[34 * 1024];
    short* Xh = (short*)smem;                    // 16 KB
    short* Bh = (short*)(smem + 16 * 1024);      // 8 KB
    short* Bl = (short*)(smem + 24 * 1024);      // 8 KB
    float* Cb = (float*)smem;                    // 64*132*4 = 33792 B

    int t  = threadIdx.x;
    int p0 = blockIdx.x * 128;
    int b  = p0 >> 17;
    int s0 = p0 & (DHW - 1);
    const unsigned short* uq = UVq + ((size_t)b * Cn) * DHW + s0;

    int pp = t & 127;
    int ho = t >> 7;
#pragma unroll
    for (int pass = 0; pass < 4; ++pass) {
        int in0 = pass * 16 + ho * 8;
        short8 vh;
#pragma unroll
        for (int j = 0; j < 8; ++j)
            vh[j] = (short)uq[(size_t)(in0 + j) * DHW + pp];
        int blk  = ((in0 >> 5) << 3) | (pp >> 4);
        int slot = (((in0 >> 3) & 3) << 4) | (pp & 15);
        *(short8*)&Xh[(blk * 64 + slot) * 8] = vh;
    }
#pragma unroll
    for (int pass = 0; pass < 2; ++pass) {   // 512 16B-units of Wt
        int unit = pass * 256 + t;
        int o    = unit & 63;
        int oc   = unit >> 6;
        int in0  = oc * 8;
        int blk  = ((o >> 4) << 1) | (in0 >> 5);
        int slot = (((in0 >> 3) & 3) << 4) | (o & 15);
        *(short8*)&Bh[(blk * 64 + slot) * 8] = *(const short8*)&Wth[o * 64 + in0];
        *(short8*)&Bl[(blk * 64 + slot) * 8] = *(const short8*)&Wtl[o * 64 + in0];
    }
    __syncthreads();

    int lane = t & 63;
    int w    = t >> 6;
    floatx4 acc[2][4];
#pragma unroll
    for (int mt = 0; mt < 2; ++mt)
#pragma unroll
        for (int nt = 0; nt < 4; ++nt) acc[mt][nt] = (floatx4)0.f;

    const short8* XhV = (const short8*)Xh;
    const short8* BhV = (const short8*)Bh;
    const short8* BlV = (const short8*)Bl;
#pragma unroll
    for (int ks = 0; ks < 2; ++ks) {
        short8 ah0 = XhV[(ks * 8 + w * 2 + 0) * 64 + lane];
        short8 ah1 = XhV[(ks * 8 + w * 2 + 1) * 64 + lane];
#pragma unroll
        for (int nt = 0; nt < 4; ++nt) {
            short8 bh = BhV[(nt * 2 + ks) * 64 + lane];
            short8 bl = BlV[(nt * 2 + ks) * 64 + lane];
            acc[0][nt] = __builtin_amdgcn_mfma_f32_16x16x32_bf16(ah0, bl, acc[0][nt], 0, 0, 0);
            acc[0][nt] = __builtin_amdgcn_mfma_f32_16x16x32_bf16(ah0, bh, acc[0][nt], 0, 0, 0);
            acc[1][nt] = __builtin_amdgcn_mfma_f32_16x16x32_bf16(ah1, bl, acc[1][nt], 0, 0, 0);
            acc[1][nt] = __builtin_amdgcn_mfma_f32_16x16x32_bf16(ah1, bh, acc[1][nt], 0, 0, 0);
        }
    }

    __syncthreads();
    int outc = lane & 15;
    int quad = lane >> 4;
#pragma unroll
    for (int mt = 0; mt < 2; ++mt)
#pragma unroll
        for (int nt = 0; nt < 4; ++nt) {
            int o   = nt * 16 + outc;
            int pos = w * 32 + mt * 16 + quad * 4;
            *(floatx4*)&Cb[o * 132 + pos] = acc[mt][nt];
        }
    __syncthreads();

    int xr = (t & 31) * 4;
    int ob = t >> 5;
#pragma unroll
    for (int pass = 0; pass < 8; ++pass) {
        int o = pass * 8 + ob;
        floatx4 vv = *(const floatx4*)&Cb[o * 132 + xr];
        *(floatx4*)&out[((size_t)(b * Cn + o)) * DHW + s0 + xr] = vv;
    }
}

extern "C" void kernel_launch(void* const* d_in, const int* in_sizes, int n_in,
                              void* d_out, int out_size, void* d_ws, size_t ws_size,
                              hipStream_t stream)
{
    const float* x      = (const float*)d_in[0];
    const float* head_w = (const float*)d_in[1];
    const float* tail_w = (const float*)d_in[2];
    const float* U_w    = (const float*)d_in[3];
    const float* V_w    = (const float*)d_in[4];
    float* out = (float*)d_out;

    // ws: h fp32 (64MB) | Vp fp32 (3MB) | UVq bf16 (32MB) | split weights
    float* h   = (float*)d_ws;
    float* Vp  = h + (size_t)NELEM;
    unsigned short* UVq = (unsigned short*)(Vp + (size_t)Bn * 3 * DHW);
    short* Whh = (short*)(UVq + (size_t)NELEM);
    short* Whl = Whh + 80 * 64;
    short* Wth = Whl + 80 * 64;
    short* Wtl = Wth + 64 * 64;

    k_prep<<<1, 256, 0, stream>>>(head_w, tail_w, V_w, Whh, Whl, Wth, Wtl);
    k_headm<<<NPOS / 128, 256, 0, stream>>>(x, Whh, Whl, h, Vp);
    k_uv<<<Bn * Cn * (Hd / 2), 256, 0, stream>>>(h, Vp, U_w, UVq);
    k_tailm<<<NPOS / 128, 256, 0, stream>>>(UVq, Wth, Wtl, out);
}